// Round 4
// baseline (645.763 us; speedup 1.0000x reference)
//
#include <hip/hip_runtime.h>
#include <hip/hip_cooperative_groups.h>
#include <stdint.h>

namespace cg = cooperative_groups;

// SelfOrganizingBrain: B=1024, IN=784, E=256, NCLS=10, N=64 blocks, NJUMPS=4.
// R3: single persistent cooperative kernel (256 WGs x 1024 thr, 1 WG/CU),
// 11 phases / 10 grid.sync() -- removes 11 kernel-boundary gap+ramp+drain
// overheads (~17us each at R2's 12-dispatch structure). Phase math identical
// to R2 (validated absmax 1.2e-3). All fp32 (gumbel argmax is bit-critical).

#define BATCH 1024
#define EDIM  256
#define INDIM 784

// ---------------- threefry2x32 (exact JAX semantics, validated R0-R2) ----------------
__host__ __device__ inline uint32_t rotl32(uint32_t x, uint32_t d) {
  return (x << d) | (x >> (32u - d));
}
__host__ __device__ inline void threefry2x32(uint32_t k0, uint32_t k1,
                                             uint32_t x0, uint32_t x1,
                                             uint32_t* o0, uint32_t* o1) {
  uint32_t ks2 = k0 ^ k1 ^ 0x1BD11BDAu;
  x0 += k0; x1 += k1;
#define TF_R(a) { x0 += x1; x1 = rotl32(x1, a); x1 ^= x0; }
  TF_R(13) TF_R(15) TF_R(26) TF_R(6)   x0 += k1;  x1 += ks2 + 1u;
  TF_R(17) TF_R(29) TF_R(16) TF_R(24)  x0 += ks2; x1 += k0  + 2u;
  TF_R(13) TF_R(15) TF_R(26) TF_R(6)   x0 += k0;  x1 += k1  + 3u;
  TF_R(17) TF_R(29) TF_R(16) TF_R(24)  x0 += k1;  x1 += ks2 + 4u;
  TF_R(13) TF_R(15) TF_R(26) TF_R(6)   x0 += ks2; x1 += k0  + 5u;
#undef TF_R
  *o0 = x0; *o1 = x1;
}
__device__ inline uint32_t jax_bits12288(uint32_t k0, uint32_t k1, uint32_t L) {
  uint32_t o0, o1;
  if (L < 6144u) { threefry2x32(k0, k1, L, L + 6144u, &o0, &o1); return o0; }
  else           { threefry2x32(k0, k1, L - 6144u, L, &o0, &o1); return o1; }
}
__device__ inline float jax_uniform(uint32_t bits) {
  const float minv = 1e-6f;
  const float maxv = (float)(1.0 - 1e-06);
  const float span = maxv - minv;
  uint32_t fb = (bits >> 9) | 0x3f800000u;
  float f = __uint_as_float(fb) - 1.0f;
  float u = __fadd_rn(__fmul_rn(f, span), minv);
  return fmaxf(minv, u);
}

// ---------------- LDS union across phases (max = embed: 61952 B < 64 KB) ----------------
struct SmemE { float XS[8 * INDIM]; float P[8][128][9]; };                   // 61952 B
struct SmemA { float XS[4 * EDIM]; float P[4][256][5]; float H[EDIM][4];
               float P2[16][4][16]; float vals[4][12]; int flags[4]; };      // ~33 KB
struct SmemB { float XS[8 * EDIM]; float P[4][256][9]; float H[EDIM][12];
               int meta[4]; int rowsl[8]; float denom[8];
               int wcnt[16]; int wbase[16]; };                               // ~57.5 KB
struct SmemH { float XS[4 * EDIM]; float P[4][256][5]; float H[EDIM][4];
               float P2[16][4][16]; };                                       // ~29 KB
union Smem { SmemE e; SmemA a; SmemB b; SmemH h; };

__global__ __launch_bounds__(1024, 4) void k_fused(
    const float* __restrict__ x, const float* __restrict__ Wemb,
    const float* __restrict__ bemb,
    const float* __restrict__ stW1, const float* __restrict__ stb1,
    const float* __restrict__ stW2, const float* __restrict__ stb2,
    const float* __restrict__ aW1, const float* __restrict__ ab1,
    const float* __restrict__ aW2, const float* __restrict__ ab2,
    const float* __restrict__ oW1, const float* __restrict__ ob1,
    const float* __restrict__ oW2, const float* __restrict__ ob2,
    float* __restrict__ out,
    float* stateA, float* stateB, float* initial, float* finalb,
    int* exited, int* n_next, int* cnt0, int* cnt1) {
  __shared__ Smem sm;
  cg::grid_group grid = cg::this_grid();
  const int t = threadIdx.x;
  const int bid = blockIdx.x;

  // ================= phase E: embed (rg = bid>>1, col-half = bid&1) =================
  {
    if (bid == 0 && t < 64) cnt0[t] = 0;
    const int rg = bid >> 1, ch = bid & 1;
    const int jl = t & 127, ks = t >> 7;
    {
      const float4* src = (const float4*)(x + (size_t)rg * 8 * INDIM);
      float4* dst = (float4*)sm.e.XS;
      for (int p = t; p < (8 * INDIM) / 4; p += 1024) dst[p] = src[p];
    }
    __syncthreads();
    const int col = ch * 128 + jl;
    const int kb = (ks < 4) ? ks * 100 : 400 + (ks - 4) * 96;
    const int ke = kb + ((ks < 4) ? 100 : 96);
    float a[8] = {0.f,0.f,0.f,0.f,0.f,0.f,0.f,0.f};
#pragma unroll 2
    for (int k = kb; k < ke; k += 4) {
      const float w0 = Wemb[(k+0)*EDIM + col], w1 = Wemb[(k+1)*EDIM + col],
                  w2 = Wemb[(k+2)*EDIM + col], w3 = Wemb[(k+3)*EDIM + col];
#pragma unroll
      for (int i = 0; i < 8; i++) {
        const float4 s4 = *(const float4*)&sm.e.XS[i * INDIM + k];
        a[i] = fmaf(s4.x, w0, a[i]); a[i] = fmaf(s4.y, w1, a[i]);
        a[i] = fmaf(s4.z, w2, a[i]); a[i] = fmaf(s4.w, w3, a[i]);
      }
    }
#pragma unroll
    for (int q = 0; q < 8; q++) sm.e.P[ks][jl][q] = a[q];
    __syncthreads();
    {
      const int c2 = t & 127, i = t >> 7;
      float s = 0.f;
#pragma unroll
      for (int w = 0; w < 8; w++) s += sm.e.P[w][c2][i];
      s += bemb[ch * 128 + c2];
      const size_t idx = (size_t)(rg * 8 + i) * EDIM + ch * 128 + c2;
      stateA[idx] = s; initial[idx] = s;
    }
  }
  grid.sync();

  float* cur = stateA;
  float* nxt = stateB;
  for (int jj = 0; jj < 5; jj++) {
    float* dst = (jj < 4) ? nxt : finalb;
    int* cnt  = (jj & 1) ? cnt1 : cnt0;
    int* cntN = (jj & 1) ? cnt0 : cnt1;

    // ================= phase A: addr MLP + gumbel argmax + frozen-copy =================
    {
      const int b0 = bid * 4;
      sm.a.XS[t] = cur[(size_t)b0 * EDIM + t];   // 4 rows, coalesced
      __syncthreads();
      const int j = t & 255, ks = t >> 8;
      const int kb = ks * 64;
      float a[4] = {0.f,0.f,0.f,0.f};
#pragma unroll 2
      for (int k = kb; k < kb + 64; k += 4) {
        const float w0 = aW1[(k+0)*EDIM + j], w1 = aW1[(k+1)*EDIM + j],
                    w2 = aW1[(k+2)*EDIM + j], w3 = aW1[(k+3)*EDIM + j];
#pragma unroll
        for (int i = 0; i < 4; i++) {
          const float4 s4 = *(const float4*)&sm.a.XS[i * EDIM + k];
          a[i] = fmaf(s4.x, w0, a[i]); a[i] = fmaf(s4.y, w1, a[i]);
          a[i] = fmaf(s4.z, w2, a[i]); a[i] = fmaf(s4.w, w3, a[i]);
        }
      }
#pragma unroll
      for (int q = 0; q < 4; q++) sm.a.P[ks][j][q] = a[q];
      __syncthreads();
      {
        const int j2 = t & 255, i = t >> 8;
        float s = sm.a.P[0][j2][i] + sm.a.P[1][j2][i] + sm.a.P[2][j2][i]
                + sm.a.P[3][j2][i] + ab1[j2];
        sm.a.H[j2][i] = fmaxf(s, 0.f);
      }
      __syncthreads();
      {
        const int c = t & 15, i = (t >> 4) & 3, ksl = t >> 6;
        float a2 = 0.f;
        if (c < 12) {
          const int k0 = ksl * 16;
#pragma unroll 4
          for (int k = k0; k < k0 + 16; k++)
            a2 = fmaf(sm.a.H[k][i], aW2[k * 12 + c], a2);
        }
        sm.a.P2[ksl][i][c] = a2;
      }
      __syncthreads();
      if (t < 48) {
        const int i = t / 12, c = t % 12;
        float s = 0.f;
#pragma unroll
        for (int w = 0; w < 16; w++) s += sm.a.P2[w][i][c];
        const float logit = s + ab2[c];
        uint32_t fk0, fk1;                              // fold_in(key(42), jj)
        threefry2x32(0u, 42u, 0u, (uint32_t)jj, &fk0, &fk1);
        const uint32_t L = (uint32_t)((b0 + i) * 12 + c);
        const float u = jax_uniform(jax_bits12288(fk0, fk1, L));
        const float g = -logf(-logf(u));
        sm.a.vals[i][c] = logit + g;       // TAU=1, softmax monotone -> argmax
      }
      __syncthreads();
      if (t < 4) {
        const int b = b0 + t;
        int idx0 = 0, idx1 = 0, idx2 = 0;
        { float best = sm.a.vals[t][0];
#pragma unroll
          for (int c = 1; c < 4; c++) { float v = sm.a.vals[t][c];     if (v > best) { best = v; idx0 = c; } } }
        { float best = sm.a.vals[t][4];
#pragma unroll
          for (int c = 1; c < 4; c++) { float v = sm.a.vals[t][4 + c]; if (v > best) { best = v; idx1 = c; } } }
        { float best = sm.a.vals[t][8];
#pragma unroll
          for (int c = 1; c < 4; c++) { float v = sm.a.vals[t][8 + c]; if (v > best) { best = v; idx2 = c; } } }
        const int nn = idx0 * 16 + idx1 * 4 + idx2;
        int nxt_n;
        if (jj == 0)      { exited[b] = 0; nxt_n = nn; }
        else if (jj < 4)  {
          if (exited[b])      nxt_n = -1;
          else if (nn == 0) { exited[b] = 1; nxt_n = -1; }
          else                nxt_n = nn;
        } else              nxt_n = exited[b] ? 0 : nn;
        n_next[b] = nxt_n; sm.a.flags[t] = nxt_n;
        if (nxt_n >= 0) atomicAdd(&cnt[nxt_n], 1);
      }
      __syncthreads();
      {  // frozen rows: copy state forward from LDS
        const int i = t >> 8, jc = t & 255;
        if (sm.a.flags[i] < 0) dst[(size_t)(b0 + i) * EDIM + jc] = sm.a.XS[i * EDIM + jc];
      }
    }
    grid.sync();

    // ================= phase B: routed block eval, CHUNK=8 =================
    {
      const int c = bid;
      if (c == 0 && t < 64) cntN[t] = 0;     // zero next round's counters
      if (t < 8) sm.b.rowsl[t] = 0;
      if (t < 64) {                          // chunk assignment from counts
        const int cntv = cnt[t];
        const int nch = (cntv + 7) >> 3;
        int icnt = cntv, inch = nch;
#pragma unroll
        for (int d = 1; d < 64; d <<= 1) {
          int t1 = __shfl_up(icnt, d), t2 = __shfl_up(inch, d);
          if (t >= d) { icnt += t1; inch += t2; }
        }
        const int ench = inch - nch;
        const int total = __shfl(inch, 63);
        if (t == 0) sm.b.meta[3] = total;
        if (c >= ench && c < ench + nch) {
          sm.b.meta[0] = t; sm.b.meta[1] = c - ench;
          sm.b.meta[2] = min(8, cntv - (c - ench) * 8);
        }
      }
      __syncthreads();
      if (c < sm.b.meta[3]) {                // WG-uniform guard (no early return)
        const int n = sm.b.meta[0], local = sm.b.meta[1], m = sm.b.meta[2];

        {  // ordered row list via ballot-scan of n_next (thread t <-> row t)
          const bool flag = (n_next[t] == n);
          const unsigned long long bal = __ballot(flag);
          const int wid = t >> 6, lane = t & 63;
          if (lane == 0) sm.b.wcnt[wid] = __popcll(bal);
          __syncthreads();
          if (t == 0) { int s = 0; for (int w = 0; w < 16; w++) { sm.b.wbase[w] = s; s += sm.b.wcnt[w]; } }
          __syncthreads();
          if (flag) {
            const int rank = sm.b.wbase[wid] + __popcll(bal & ((1ull << lane) - 1ull));
            const int r0 = local * 8;
            if (rank >= r0 && rank < r0 + 8) sm.b.rowsl[rank - r0] = t;
          }
          __syncthreads();
        }

        // stage 8 rows into LDS (coalesced float4) + norms
        if (t < 512) {
          const int i = t >> 6, q = t & 63;
          const int row = sm.b.rowsl[min(i, m - 1)] & 1023;
          const float4 v = *(const float4*)(cur + (size_t)row * EDIM + q * 4);
          ((float4*)sm.b.XS)[t] = v;
          float sq = v.x*v.x + v.y*v.y + v.z*v.z + v.w*v.w;
#pragma unroll
          for (int d = 32; d >= 1; d >>= 1) sq += __shfl_xor(sq, d);
          if (q == 0) sm.b.denom[i] = sqrtf(sq) + 1e-6f;
        }
        __syncthreads();

        // layer 1: (j 256, ks 4), K-slice 64
        const int j = t & 255, ks = t >> 8;
        const int kb = ks * 64;
        const float* W1n = stW1 + (size_t)n * EDIM * EDIM;
        {
          float a[8] = {0.f,0.f,0.f,0.f,0.f,0.f,0.f,0.f};
#pragma unroll 2
          for (int k = kb; k < kb + 64; k += 4) {
            const float w0 = W1n[(k+0)*EDIM + j], w1 = W1n[(k+1)*EDIM + j],
                        w2 = W1n[(k+2)*EDIM + j], w3 = W1n[(k+3)*EDIM + j];
#pragma unroll
            for (int i = 0; i < 8; i++) {
              const float4 s4 = *(const float4*)&sm.b.XS[i * EDIM + k];
              a[i] = fmaf(s4.x, w0, a[i]); a[i] = fmaf(s4.y, w1, a[i]);
              a[i] = fmaf(s4.z, w2, a[i]); a[i] = fmaf(s4.w, w3, a[i]);
            }
          }
#pragma unroll
          for (int q = 0; q < 8; q++) sm.b.P[ks][j][q] = a[q];
        }
        __syncthreads();
        {  // H reduce: 2 outputs/thread
          const int j2 = t & 255, ih = t >> 8;
          const float bb = stb1[(size_t)n * EDIM + j2];
#pragma unroll
          for (int qq = 0; qq < 2; qq++) {
            const int i = ih + qq * 4;
            float s = sm.b.P[0][j2][i] + sm.b.P[1][j2][i] + sm.b.P[2][j2][i]
                    + sm.b.P[3][j2][i] + bb;
            sm.b.H[j2][i] = fmaxf(s, 0.f);
          }
        }
        __syncthreads();
        // layer 2: per k: 1 w load + 2 LDS b128 broadcasts + 8 FMA
        const float* W2n = stW2 + (size_t)n * EDIM * EDIM;
        {
          float a[8] = {0.f,0.f,0.f,0.f,0.f,0.f,0.f,0.f};
#pragma unroll 4
          for (int k = kb; k < kb + 64; k++) {
            const float w = W2n[k*EDIM + j];
            const float4 h0 = *(const float4*)&sm.b.H[k][0];
            const float4 h1 = *(const float4*)&sm.b.H[k][4];
            a[0] = fmaf(h0.x, w, a[0]); a[1] = fmaf(h0.y, w, a[1]);
            a[2] = fmaf(h0.z, w, a[2]); a[3] = fmaf(h0.w, w, a[3]);
            a[4] = fmaf(h1.x, w, a[4]); a[5] = fmaf(h1.y, w, a[5]);
            a[6] = fmaf(h1.z, w, a[6]); a[7] = fmaf(h1.w, w, a[7]);
          }
#pragma unroll
          for (int q = 0; q < 8; q++) sm.b.P[ks][j][q] = a[q];
        }
        __syncthreads();
        {  // final reduce + relu + /norm (+ initial on final round)
          const int col = t & 255, ih = t >> 8;
          const float bb2 = stb2[(size_t)n * EDIM + col];
#pragma unroll
          for (int qq = 0; qq < 2; qq++) {
            const int i = ih + qq * 4;
            if (i < m) {
              float s = sm.b.P[0][col][i] + sm.b.P[1][col][i] + sm.b.P[2][col][i]
                      + sm.b.P[3][col][i] + bb2;
              float v = fmaxf(s, 0.f) / sm.b.denom[i];
              const int row = sm.b.rowsl[i] & 1023;
              if (jj == 4) v += initial[(size_t)row * EDIM + col];
              dst[(size_t)row * EDIM + col] = v;
            }
          }
        }
      }
    }
    grid.sync();
    if (jj < 4) { float* tmp = cur; cur = nxt; nxt = tmp; }
  }

  // ================= phase H: output head (4 rows/WG) =================
  {
    const int b0 = bid * 4;
    sm.h.XS[t] = finalb[(size_t)b0 * EDIM + t];
    __syncthreads();
    const int j = t & 255, ks = t >> 8;
    const int kb = ks * 64;
    float a[4] = {0.f,0.f,0.f,0.f};
#pragma unroll 2
    for (int k = kb; k < kb + 64; k += 4) {
      const float w0 = oW1[(k+0)*EDIM + j], w1 = oW1[(k+1)*EDIM + j],
                  w2 = oW1[(k+2)*EDIM + j], w3 = oW1[(k+3)*EDIM + j];
#pragma unroll
      for (int i = 0; i < 4; i++) {
        const float4 s4 = *(const float4*)&sm.h.XS[i * EDIM + k];
        a[i] = fmaf(s4.x, w0, a[i]); a[i] = fmaf(s4.y, w1, a[i]);
        a[i] = fmaf(s4.z, w2, a[i]); a[i] = fmaf(s4.w, w3, a[i]);
      }
    }
#pragma unroll
    for (int q = 0; q < 4; q++) sm.h.P[ks][j][q] = a[q];
    __syncthreads();
    {
      const int j2 = t & 255, i = t >> 8;
      float s = sm.h.P[0][j2][i] + sm.h.P[1][j2][i] + sm.h.P[2][j2][i]
              + sm.h.P[3][j2][i] + ob1[j2];
      sm.h.H[j2][i] = fmaxf(s, 0.f);
    }
    __syncthreads();
    {
      const int c = t & 15, i = (t >> 4) & 3, ksl = t >> 6;
      float a2 = 0.f;
      if (c < 10) {
        const int k0 = ksl * 16;
#pragma unroll 4
        for (int k = k0; k < k0 + 16; k++)
          a2 = fmaf(sm.h.H[k][i], oW2[k * 10 + c], a2);
      }
      sm.h.P2[ksl][i][c] = a2;
    }
    __syncthreads();
    if (t < 40) {
      const int i = t / 10, c = t % 10;
      float s = 0.f;
#pragma unroll
      for (int w = 0; w < 16; w++) s += sm.h.P2[w][i][c];
      out[(size_t)(b0 + i) * 10 + c] = s + ob2[c];
    }
  }
}

// ---------------- launch ----------------
extern "C" void kernel_launch(void* const* d_in, const int* in_sizes, int n_in,
                              void* d_out, int out_size, void* d_ws, size_t ws_size,
                              hipStream_t stream) {
  const float* x    = (const float*)d_in[0];
  const float* Wemb = (const float*)d_in[1];
  const float* bemb = (const float*)d_in[2];
  const float* stW1 = (const float*)d_in[3];
  const float* stb1 = (const float*)d_in[4];
  const float* stW2 = (const float*)d_in[5];
  const float* stb2 = (const float*)d_in[6];
  const float* aW1  = (const float*)d_in[7];
  const float* ab1  = (const float*)d_in[8];
  const float* aW2  = (const float*)d_in[9];
  const float* ab2  = (const float*)d_in[10];
  const float* oW1  = (const float*)d_in[11];
  const float* ob1  = (const float*)d_in[12];
  const float* oW2  = (const float*)d_in[13];
  const float* ob2  = (const float*)d_in[14];
  float* out = (float*)d_out;

  char* ws = (char*)d_ws;
  auto alloc = [&](size_t bytes) { char* p = ws; ws += (bytes + 255) & ~(size_t)255; return p; };
  float* stateA  = (float*)alloc((size_t)BATCH * EDIM * 4);
  float* stateB  = (float*)alloc((size_t)BATCH * EDIM * 4);
  float* initial = (float*)alloc((size_t)BATCH * EDIM * 4);
  float* finalb  = (float*)alloc((size_t)BATCH * EDIM * 4);
  int* exited = (int*)alloc(BATCH * 4);
  int* n_next = (int*)alloc(BATCH * 4);
  int* cnt0   = (int*)alloc(64 * 4);
  int* cnt1   = (int*)alloc(64 * 4);

  void* args[] = {
    (void*)&x, (void*)&Wemb, (void*)&bemb,
    (void*)&stW1, (void*)&stb1, (void*)&stW2, (void*)&stb2,
    (void*)&aW1, (void*)&ab1, (void*)&aW2, (void*)&ab2,
    (void*)&oW1, (void*)&ob1, (void*)&oW2, (void*)&ob2,
    (void*)&out,
    (void*)&stateA, (void*)&stateB, (void*)&initial, (void*)&finalb,
    (void*)&exited, (void*)&n_next, (void*)&cnt0, (void*)&cnt1
  };
  hipLaunchCooperativeKernel((const void*)k_fused, dim3(256), dim3(1024),
                             args, 0, stream);
}

// Round 5
// 292.603 us; speedup vs baseline: 2.2070x; 2.2070x over previous
//
#include <hip/hip_runtime.h>
#include <stdint.h>

// SelfOrganizingBrain: B=1024, IN=784, E=256, NCLS=10, N=64 blocks, NJUMPS=4.
// R4: revert cooperative fusion (grid.sync invalidates per-XCD L2 -> 214MB HBM
// refetch, 646us). Instead: 6 dispatches via epilogue fusion:
//   E+A0 -> B0+A1 -> B1+A2 -> B2+A3 -> B3+A4 -> B4+head
// - addr MLP for round j+1 fused into B_j's epilogue (rows are in LDS)
// - in-place state (rows uniquely owned per round; frozen rows untouched)
// - no global atomics: per-WG LDS histogram of nn[round]; exits write -1
//   into nn[s..4] (sole writer per row -> deterministic, replay-safe)
// All fp32 (gumbel argmax is bit-critical vs JAX threefry).

#define BATCH 1024
#define EDIM  256
#define INDIM 784
#define GRID_B 192   // max chunks = sum ceil(cnt_n/8) <= 128 + 56 = 184

// ---------------- threefry2x32 (exact JAX semantics, validated R0-R3) ----------------
__host__ __device__ inline uint32_t rotl32(uint32_t x, uint32_t d) {
  return (x << d) | (x >> (32u - d));
}
__host__ __device__ inline void threefry2x32(uint32_t k0, uint32_t k1,
                                             uint32_t x0, uint32_t x1,
                                             uint32_t* o0, uint32_t* o1) {
  uint32_t ks2 = k0 ^ k1 ^ 0x1BD11BDAu;
  x0 += k0; x1 += k1;
#define TF_R(a) { x0 += x1; x1 = rotl32(x1, a); x1 ^= x0; }
  TF_R(13) TF_R(15) TF_R(26) TF_R(6)   x0 += k1;  x1 += ks2 + 1u;
  TF_R(17) TF_R(29) TF_R(16) TF_R(24)  x0 += ks2; x1 += k0  + 2u;
  TF_R(13) TF_R(15) TF_R(26) TF_R(6)   x0 += k0;  x1 += k1  + 3u;
  TF_R(17) TF_R(29) TF_R(16) TF_R(24)  x0 += k1;  x1 += ks2 + 4u;
  TF_R(13) TF_R(15) TF_R(26) TF_R(6)   x0 += ks2; x1 += k0  + 5u;
#undef TF_R
  *o0 = x0; *o1 = x1;
}
__device__ inline uint32_t jax_bits12288(uint32_t k0, uint32_t k1, uint32_t L) {
  uint32_t o0, o1;
  if (L < 6144u) { threefry2x32(k0, k1, L, L + 6144u, &o0, &o1); return o0; }
  else           { threefry2x32(k0, k1, L - 6144u, L, &o0, &o1); return o1; }
}
__device__ inline float jax_uniform(uint32_t bits) {
  const float minv = 1e-6f;
  const float maxv = (float)(1.0 - 1e-06);
  const float span = maxv - minv;
  uint32_t fb = (bits >> 9) | 0x3f800000u;
  float f = __uint_as_float(fb) - 1.0f;
  float u = __fadd_rn(__fmul_rn(f, span), minv);
  return fmaxf(minv, u);
}
// gumbel value for (row b, logit c) at address-step s
__device__ inline float gumbel_val(int s, int b, int c) {
  uint32_t fk0, fk1;
  threefry2x32(0u, 42u, 0u, (uint32_t)s, &fk0, &fk1);   // fold_in(key(42), s)
  const uint32_t L = (uint32_t)(b * 12 + c);
  const float u = jax_uniform(jax_bits12288(fk0, fk1, L));
  return -logf(-logf(u));
}

// 3x argmax-of-4 -> block index
__device__ inline int addr_argmax(const float* v) {
  int i0 = 0, i1 = 0, i2 = 0;
  { float b = v[0];
    for (int c = 1; c < 4; c++) { float x = v[c];     if (x > b) { b = x; i0 = c; } } }
  { float b = v[4];
    for (int c = 1; c < 4; c++) { float x = v[4 + c]; if (x > b) { b = x; i1 = c; } } }
  { float b = v[8];
    for (int c = 1; c < 4; c++) { float x = v[8 + c]; if (x > b) { b = x; i2 = c; } } }
  return i0 * 16 + i1 * 4 + i2;
}

// ============ E + A0: embed 4 rows/WG (full cols) + addr step 0 ============
__global__ __launch_bounds__(1024, 4) void k_embed_a0(
    const float* __restrict__ x, const float* __restrict__ Wemb,
    const float* __restrict__ bemb,
    const float* __restrict__ aW1, const float* __restrict__ ab1,
    const float* __restrict__ aW2, const float* __restrict__ ab2,
    float* __restrict__ state, float* __restrict__ initial,
    int* __restrict__ nn_all) {
  __shared__ float XS[4 * INDIM];      // 12.5 KB x-rows
  __shared__ float P[4][256][5];       // 20.5 KB partials
  __shared__ float SS[4 * EDIM];       // 4 KB new-state rows
  __shared__ float H[EDIM][4];         // 4 KB
  __shared__ float P2[16][4][16];      // 4 KB
  __shared__ float vals[4][12];
  const int t = threadIdx.x, b0 = blockIdx.x * 4;

  { // stage 4 x-rows, coalesced float4 (4*784/4 = 784)
    const float4* src = (const float4*)(x + (size_t)b0 * INDIM);
    float4* dst = (float4*)XS;
    for (int p = t; p < INDIM; p += 1024) dst[p] = src[p];
  }
  __syncthreads();

  const int j = t & 255, ks = t >> 8;
  { // embed layer: K-slices of 196 (196 = 49*4)
    const int kb = ks * 196;
    float a[4] = {0.f,0.f,0.f,0.f};
#pragma unroll 2
    for (int k = kb; k < kb + 196; k += 4) {
      const float w0 = Wemb[(k+0)*EDIM + j], w1 = Wemb[(k+1)*EDIM + j],
                  w2 = Wemb[(k+2)*EDIM + j], w3 = Wemb[(k+3)*EDIM + j];
#pragma unroll
      for (int i = 0; i < 4; i++) {
        const float4 s4 = *(const float4*)&XS[i * INDIM + k];
        a[i] = fmaf(s4.x, w0, a[i]); a[i] = fmaf(s4.y, w1, a[i]);
        a[i] = fmaf(s4.z, w2, a[i]); a[i] = fmaf(s4.w, w3, a[i]);
      }
    }
#pragma unroll
    for (int q = 0; q < 4; q++) P[ks][j][q] = a[q];
  }
  __syncthreads();
  { // reduce + bias -> SS + global
    const int j2 = t & 255, i = t >> 8;
    float s = P[0][j2][i] + P[1][j2][i] + P[2][j2][i] + P[3][j2][i] + bemb[j2];
    SS[i * EDIM + j2] = s;
    const size_t idx = (size_t)(b0 + i) * EDIM + j2;
    state[idx] = s; initial[idx] = s;
  }
  __syncthreads();

  // ---- A0: addr MLP on SS (4 rows) ----
  { const int kb = ks * 64;
    float a[4] = {0.f,0.f,0.f,0.f};
#pragma unroll 2
    for (int k = kb; k < kb + 64; k += 4) {
      const float w0 = aW1[(k+0)*EDIM + j], w1 = aW1[(k+1)*EDIM + j],
                  w2 = aW1[(k+2)*EDIM + j], w3 = aW1[(k+3)*EDIM + j];
#pragma unroll
      for (int i = 0; i < 4; i++) {
        const float4 s4 = *(const float4*)&SS[i * EDIM + k];
        a[i] = fmaf(s4.x, w0, a[i]); a[i] = fmaf(s4.y, w1, a[i]);
        a[i] = fmaf(s4.z, w2, a[i]); a[i] = fmaf(s4.w, w3, a[i]);
      }
    }
#pragma unroll
    for (int q = 0; q < 4; q++) P[ks][j][q] = a[q];
  }
  __syncthreads();
  { const int j2 = t & 255, i = t >> 8;
    float s = P[0][j2][i] + P[1][j2][i] + P[2][j2][i] + P[3][j2][i] + ab1[j2];
    H[j2][i] = fmaxf(s, 0.f);
  }
  __syncthreads();
  { const int c = t & 15, i = (t >> 4) & 3, ksl = t >> 6;   // 16 slices of 16
    float a2 = 0.f;
    if (c < 12) {
      const int k0 = ksl * 16;
#pragma unroll 4
      for (int k = k0; k < k0 + 16; k++)
        a2 = fmaf(H[k][i], aW2[k * 12 + c], a2);
    }
    P2[ksl][i][c] = a2;
  }
  __syncthreads();
  if (t < 48) {
    const int i = t / 12, c = t % 12;
    float s = 0.f;
#pragma unroll
    for (int w = 0; w < 16; w++) s += P2[w][i][c];
    vals[i][c] = s + ab2[c] + gumbel_val(0, b0 + i, c);
  }
  __syncthreads();
  if (t < 4) nn_all[b0 + t] = addr_argmax(vals[t]);   // step 0: no exits
}

// ============ shared LDS layout for B kernels ============
struct BShared {
  float XS[8 * EDIM];     // 8 KB: block-input rows, then new-state rows
  float P[4][256][9];     // 36.9 KB partials
  float H[EDIM][12];      // 12.3 KB (8 rows used, stride 12 keeps b128 align)
  float P2[8][8][16];     // 4 KB
  float vals[8][12];
  float denom[8];
  int rowsl[8];
  int hist[64];
  int meta[4];
  int wcnt[16], wbase[16];
};

// common body: chunk-assign + stage + 2-layer block eval; returns m (rows) via ref
// (inlined manually in both kernels to keep register allocation tight)

// ============ B_j + A_{j+1}: routed blocks, CHUNK=8, fused addr epilogue ============
__global__ __launch_bounds__(1024, 4) void k_block_mid(
    float* __restrict__ state,
    const float* __restrict__ W1, const float* __restrict__ b1,
    const float* __restrict__ W2, const float* __restrict__ b2,
    const float* __restrict__ aW1, const float* __restrict__ ab1,
    const float* __restrict__ aW2, const float* __restrict__ ab2,
    int* __restrict__ nn_all, int rstep) {   // reads nn_all[rstep], A-step = rstep+1
  __shared__ BShared sm;
  const int t = threadIdx.x, c = blockIdx.x;
  const int* nnj = nn_all + rstep * BATCH;

  // 1. LDS histogram of this round's addresses
  if (t < 64) sm.hist[t] = 0;
  __syncthreads();
  const int vmy = nnj[t];
  if (vmy >= 0) atomicAdd(&sm.hist[vmy], 1);
  __syncthreads();
  // 2. chunk assignment (wave 0)
  if (t < 64) {
    const int cnt = sm.hist[t];
    const int nch = (cnt + 7) >> 3;
    int icnt = cnt, inch = nch;
#pragma unroll
    for (int d = 1; d < 64; d <<= 1) {
      int t1 = __shfl_up(icnt, d), t2 = __shfl_up(inch, d);
      if (t >= d) { icnt += t1; inch += t2; }
    }
    const int ench = inch - nch;
    if (t == 63) sm.meta[3] = inch;
    if (c >= ench && c < ench + nch) {
      sm.meta[0] = t; sm.meta[1] = c - ench;
      sm.meta[2] = min(8, cnt - (c - ench) * 8);
    }
  }
  if (t < 8) sm.rowsl[t] = 0;
  __syncthreads();
  if (c >= sm.meta[3]) return;              // WG-uniform
  const int n = sm.meta[0], local = sm.meta[1], m = sm.meta[2];

  // 3. ballot-rank row list
  {
    const bool flag = (vmy == n);
    const unsigned long long bal = __ballot(flag);
    const int wid = t >> 6, lane = t & 63;
    if (lane == 0) sm.wcnt[wid] = __popcll(bal);
    __syncthreads();
    if (t == 0) { int s = 0; for (int w = 0; w < 16; w++) { sm.wbase[w] = s; s += sm.wcnt[w]; } }
    __syncthreads();
    if (flag) {
      const int rank = sm.wbase[wid] + __popcll(bal & ((1ull << lane) - 1ull));
      const int r0 = local * 8;
      if (rank >= r0 && rank < r0 + 8) sm.rowsl[rank - r0] = t;
    }
    __syncthreads();
  }

  // 4. stage 8 rows + norms
  if (t < 512) {
    const int i = t >> 6, q = t & 63;
    const int row = sm.rowsl[min(i, m - 1)] & 1023;
    const float4 v = *(const float4*)(state + (size_t)row * EDIM + q * 4);
    ((float4*)sm.XS)[t] = v;
    float sq = v.x*v.x + v.y*v.y + v.z*v.z + v.w*v.w;
#pragma unroll
    for (int d = 32; d >= 1; d >>= 1) sq += __shfl_xor(sq, d);
    if (q == 0) sm.denom[i] = sqrtf(sq) + 1e-6f;
  }
  __syncthreads();

  const int j = t & 255, ks = t >> 8;
  const int kb = ks * 64;
  // 5. layer 1
  { const float* W1n = W1 + (size_t)n * EDIM * EDIM;
    float a[8] = {0.f,0.f,0.f,0.f,0.f,0.f,0.f,0.f};
#pragma unroll 2
    for (int k = kb; k < kb + 64; k += 4) {
      const float w0 = W1n[(k+0)*EDIM + j], w1 = W1n[(k+1)*EDIM + j],
                  w2 = W1n[(k+2)*EDIM + j], w3 = W1n[(k+3)*EDIM + j];
#pragma unroll
      for (int i = 0; i < 8; i++) {
        const float4 s4 = *(const float4*)&sm.XS[i * EDIM + k];
        a[i] = fmaf(s4.x, w0, a[i]); a[i] = fmaf(s4.y, w1, a[i]);
        a[i] = fmaf(s4.z, w2, a[i]); a[i] = fmaf(s4.w, w3, a[i]);
      }
    }
#pragma unroll
    for (int q = 0; q < 8; q++) sm.P[ks][j][q] = a[q];
  }
  __syncthreads();
  { const int j2 = t & 255, ih = t >> 8;
    const float bb = b1[(size_t)n * EDIM + j2];
#pragma unroll
    for (int qq = 0; qq < 2; qq++) {
      const int i = ih + qq * 4;
      float s = sm.P[0][j2][i] + sm.P[1][j2][i] + sm.P[2][j2][i] + sm.P[3][j2][i] + bb;
      sm.H[j2][i] = fmaxf(s, 0.f);
    }
  }
  __syncthreads();
  // 6. layer 2
  { const float* W2n = W2 + (size_t)n * EDIM * EDIM;
    float a[8] = {0.f,0.f,0.f,0.f,0.f,0.f,0.f,0.f};
#pragma unroll 4
    for (int k = kb; k < kb + 64; k++) {
      const float w = W2n[k*EDIM + j];
      const float4 h0 = *(const float4*)&sm.H[k][0];
      const float4 h1 = *(const float4*)&sm.H[k][4];
      a[0] = fmaf(h0.x, w, a[0]); a[1] = fmaf(h0.y, w, a[1]);
      a[2] = fmaf(h0.z, w, a[2]); a[3] = fmaf(h0.w, w, a[3]);
      a[4] = fmaf(h1.x, w, a[4]); a[5] = fmaf(h1.y, w, a[5]);
      a[6] = fmaf(h1.z, w, a[6]); a[7] = fmaf(h1.w, w, a[7]);
    }
#pragma unroll
    for (int q = 0; q < 8; q++) sm.P[ks][j][q] = a[q];
  }
  __syncthreads();
  // 7. final reduce: new state -> global (in-place) + XS
  { const int col = t & 255, ih = t >> 8;
    const float bb2 = b2[(size_t)n * EDIM + col];
#pragma unroll
    for (int qq = 0; qq < 2; qq++) {
      const int i = ih + qq * 4;
      if (i < m) {
        float s = sm.P[0][col][i] + sm.P[1][col][i] + sm.P[2][col][i] + sm.P[3][col][i] + bb2;
        float v = fmaxf(s, 0.f) / sm.denom[i];
        const int row = sm.rowsl[i] & 1023;
        state[(size_t)row * EDIM + col] = v;
        sm.XS[i * EDIM + col] = v;
      }
    }
  }
  __syncthreads();

  // ---- A_{rstep+1}: addr MLP on the 8 new rows ----
  { float a[8] = {0.f,0.f,0.f,0.f,0.f,0.f,0.f,0.f};
#pragma unroll 2
    for (int k = kb; k < kb + 64; k += 4) {
      const float w0 = aW1[(k+0)*EDIM + j], w1 = aW1[(k+1)*EDIM + j],
                  w2 = aW1[(k+2)*EDIM + j], w3 = aW1[(k+3)*EDIM + j];
#pragma unroll
      for (int i = 0; i < 8; i++) {
        const float4 s4 = *(const float4*)&sm.XS[i * EDIM + k];
        a[i] = fmaf(s4.x, w0, a[i]); a[i] = fmaf(s4.y, w1, a[i]);
        a[i] = fmaf(s4.z, w2, a[i]); a[i] = fmaf(s4.w, w3, a[i]);
      }
    }
#pragma unroll
    for (int q = 0; q < 8; q++) sm.P[ks][j][q] = a[q];
  }
  __syncthreads();
  { const int j2 = t & 255, ih = t >> 8;
    const float bb = ab1[j2];
#pragma unroll
    for (int qq = 0; qq < 2; qq++) {
      const int i = ih + qq * 4;
      float s = sm.P[0][j2][i] + sm.P[1][j2][i] + sm.P[2][j2][i] + sm.P[3][j2][i] + bb;
      sm.H[j2][i] = fmaxf(s, 0.f);
    }
  }
  __syncthreads();
  { const int cc = t & 15, i = (t >> 4) & 7, ksl = t >> 7;  // 8 slices of 32
    float a2 = 0.f;
    if (cc < 12) {
      const int k0 = ksl * 32;
#pragma unroll 4
      for (int k = k0; k < k0 + 32; k++)
        a2 = fmaf(sm.H[k][i], aW2[k * 12 + cc], a2);
    }
    sm.P2[ksl][i][cc] = a2;
  }
  __syncthreads();
  if (t < 96) {
    const int i = t / 12, cc = t % 12;
    float s = 0.f;
#pragma unroll
    for (int w = 0; w < 8; w++) s += sm.P2[w][i][cc];
    const int row = sm.rowsl[i] & 1023;
    sm.vals[i][cc] = s + ab2[cc] + gumbel_val(rstep + 1, row, cc);
  }
  __syncthreads();
  if (t < 8 && t < m) {
    const int b = sm.rowsl[t] & 1023;
    const int nn = addr_argmax(sm.vals[t]);
    const int s = rstep + 1;
    if (s < 4) {
      if (nn == 0) {                      // exits now: freeze for rounds s..4
        for (int q = s; q <= 4; q++) nn_all[q * BATCH + b] = -1;
      } else nn_all[s * BATCH + b] = nn;
    } else {
      nn_all[4 * BATCH + b] = nn;         // step 4: no exit logic
    }
  }
}

// ============ B4 + head: final routed blocks (+initial), output head ============
__global__ __launch_bounds__(1024, 4) void k_block_final(
    const float* __restrict__ state,
    const float* __restrict__ W1, const float* __restrict__ b1,
    const float* __restrict__ W2, const float* __restrict__ b2,
    const float* __restrict__ initial,
    const float* __restrict__ oW1, const float* __restrict__ ob1,
    const float* __restrict__ oW2, const float* __restrict__ ob2,
    const int* __restrict__ nn4, float* __restrict__ out) {
  __shared__ BShared sm;
  const int t = threadIdx.x, c = blockIdx.x;

  // histogram with -1 -> block 0 remap (exited rows re-enter at origin)
  if (t < 64) sm.hist[t] = 0;
  __syncthreads();
  int vmy = nn4[t];
  if (vmy < 0) vmy = 0;
  atomicAdd(&sm.hist[vmy], 1);
  __syncthreads();
  if (t < 64) {
    const int cnt = sm.hist[t];
    const int nch = (cnt + 7) >> 3;
    int icnt = cnt, inch = nch;
#pragma unroll
    for (int d = 1; d < 64; d <<= 1) {
      int t1 = __shfl_up(icnt, d), t2 = __shfl_up(inch, d);
      if (t >= d) { icnt += t1; inch += t2; }
    }
    const int ench = inch - nch;
    if (t == 63) sm.meta[3] = inch;
    if (c >= ench && c < ench + nch) {
      sm.meta[0] = t; sm.meta[1] = c - ench;
      sm.meta[2] = min(8, cnt - (c - ench) * 8);
    }
  }
  if (t < 8) sm.rowsl[t] = 0;
  __syncthreads();
  if (c >= sm.meta[3]) return;
  const int n = sm.meta[0], local = sm.meta[1], m = sm.meta[2];

  {
    const bool flag = (vmy == n);
    const unsigned long long bal = __ballot(flag);
    const int wid = t >> 6, lane = t & 63;
    if (lane == 0) sm.wcnt[wid] = __popcll(bal);
    __syncthreads();
    if (t == 0) { int s = 0; for (int w = 0; w < 16; w++) { sm.wbase[w] = s; s += sm.wcnt[w]; } }
    __syncthreads();
    if (flag) {
      const int rank = sm.wbase[wid] + __popcll(bal & ((1ull << lane) - 1ull));
      const int r0 = local * 8;
      if (rank >= r0 && rank < r0 + 8) sm.rowsl[rank - r0] = t;
    }
    __syncthreads();
  }

  if (t < 512) {
    const int i = t >> 6, q = t & 63;
    const int row = sm.rowsl[min(i, m - 1)] & 1023;
    const float4 v = *(const float4*)(state + (size_t)row * EDIM + q * 4);
    ((float4*)sm.XS)[t] = v;
    float sq = v.x*v.x + v.y*v.y + v.z*v.z + v.w*v.w;
#pragma unroll
    for (int d = 32; d >= 1; d >>= 1) sq += __shfl_xor(sq, d);
    if (q == 0) sm.denom[i] = sqrtf(sq) + 1e-6f;
  }
  __syncthreads();

  const int j = t & 255, ks = t >> 8;
  const int kb = ks * 64;
  { const float* W1n = W1 + (size_t)n * EDIM * EDIM;
    float a[8] = {0.f,0.f,0.f,0.f,0.f,0.f,0.f,0.f};
#pragma unroll 2
    for (int k = kb; k < kb + 64; k += 4) {
      const float w0 = W1n[(k+0)*EDIM + j], w1 = W1n[(k+1)*EDIM + j],
                  w2 = W1n[(k+2)*EDIM + j], w3 = W1n[(k+3)*EDIM + j];
#pragma unroll
      for (int i = 0; i < 8; i++) {
        const float4 s4 = *(const float4*)&sm.XS[i * EDIM + k];
        a[i] = fmaf(s4.x, w0, a[i]); a[i] = fmaf(s4.y, w1, a[i]);
        a[i] = fmaf(s4.z, w2, a[i]); a[i] = fmaf(s4.w, w3, a[i]);
      }
    }
#pragma unroll
    for (int q = 0; q < 8; q++) sm.P[ks][j][q] = a[q];
  }
  __syncthreads();
  { const int j2 = t & 255, ih = t >> 8;
    const float bb = b1[(size_t)n * EDIM + j2];
#pragma unroll
    for (int qq = 0; qq < 2; qq++) {
      const int i = ih + qq * 4;
      float s = sm.P[0][j2][i] + sm.P[1][j2][i] + sm.P[2][j2][i] + sm.P[3][j2][i] + bb;
      sm.H[j2][i] = fmaxf(s, 0.f);
    }
  }
  __syncthreads();
  { const float* W2n = W2 + (size_t)n * EDIM * EDIM;
    float a[8] = {0.f,0.f,0.f,0.f,0.f,0.f,0.f,0.f};
#pragma unroll 4
    for (int k = kb; k < kb + 64; k++) {
      const float w = W2n[k*EDIM + j];
      const float4 h0 = *(const float4*)&sm.H[k][0];
      const float4 h1 = *(const float4*)&sm.H[k][4];
      a[0] = fmaf(h0.x, w, a[0]); a[1] = fmaf(h0.y, w, a[1]);
      a[2] = fmaf(h0.z, w, a[2]); a[3] = fmaf(h0.w, w, a[3]);
      a[4] = fmaf(h1.x, w, a[4]); a[5] = fmaf(h1.y, w, a[5]);
      a[6] = fmaf(h1.z, w, a[6]); a[7] = fmaf(h1.w, w, a[7]);
    }
#pragma unroll
    for (int q = 0; q < 8; q++) sm.P[ks][j][q] = a[q];
  }
  __syncthreads();
  { // final_output = relu(.)/denom + initial -> XS (head input; no global state write)
    const int col = t & 255, ih = t >> 8;
    const float bb2 = b2[(size_t)n * EDIM + col];
#pragma unroll
    for (int qq = 0; qq < 2; qq++) {
      const int i = ih + qq * 4;
      if (i < m) {
        float s = sm.P[0][col][i] + sm.P[1][col][i] + sm.P[2][col][i] + sm.P[3][col][i] + bb2;
        float v = fmaxf(s, 0.f) / sm.denom[i];
        const int row = sm.rowsl[i] & 1023;
        v += initial[(size_t)row * EDIM + col];
        sm.XS[i * EDIM + col] = v;
      }
    }
  }
  __syncthreads();

  // ---- head: relu(fo@oW1+ob1)@oW2+ob2 for the 8 rows ----
  { float a[8] = {0.f,0.f,0.f,0.f,0.f,0.f,0.f,0.f};
#pragma unroll 2
    for (int k = kb; k < kb + 64; k += 4) {
      const float w0 = oW1[(k+0)*EDIM + j], w1 = oW1[(k+1)*EDIM + j],
                  w2 = oW1[(k+2)*EDIM + j], w3 = oW1[(k+3)*EDIM + j];
#pragma unroll
      for (int i = 0; i < 8; i++) {
        const float4 s4 = *(const float4*)&sm.XS[i * EDIM + k];
        a[i] = fmaf(s4.x, w0, a[i]); a[i] = fmaf(s4.y, w1, a[i]);
        a[i] = fmaf(s4.z, w2, a[i]); a[i] = fmaf(s4.w, w3, a[i]);
      }
    }
#pragma unroll
    for (int q = 0; q < 8; q++) sm.P[ks][j][q] = a[q];
  }
  __syncthreads();
  { const int j2 = t & 255, ih = t >> 8;
    const float bb = ob1[j2];
#pragma unroll
    for (int qq = 0; qq < 2; qq++) {
      const int i = ih + qq * 4;
      float s = sm.P[0][j2][i] + sm.P[1][j2][i] + sm.P[2][j2][i] + sm.P[3][j2][i] + bb;
      sm.H[j2][i] = fmaxf(s, 0.f);
    }
  }
  __syncthreads();
  { const int cc = t & 15, i = (t >> 4) & 7, ksl = t >> 7;  // 8 slices of 32
    float a2 = 0.f;
    if (cc < 10) {
      const int k0 = ksl * 32;
#pragma unroll 4
      for (int k = k0; k < k0 + 32; k++)
        a2 = fmaf(sm.H[k][i], oW2[k * 10 + cc], a2);
    }
    sm.P2[ksl][i][cc] = a2;
  }
  __syncthreads();
  if (t < 80) {
    const int i = t / 10, cc = t % 10;
    if (i < m) {
      float s = 0.f;
#pragma unroll
      for (int w = 0; w < 8; w++) s += sm.P2[w][i][cc];
      const int row = sm.rowsl[i] & 1023;
      out[(size_t)row * 10 + cc] = s + ob2[cc];
    }
  }
}

// ---------------- launch: 6 dispatches ----------------
extern "C" void kernel_launch(void* const* d_in, const int* in_sizes, int n_in,
                              void* d_out, int out_size, void* d_ws, size_t ws_size,
                              hipStream_t stream) {
  const float* x    = (const float*)d_in[0];
  const float* Wemb = (const float*)d_in[1];
  const float* bemb = (const float*)d_in[2];
  const float* stW1 = (const float*)d_in[3];
  const float* stb1 = (const float*)d_in[4];
  const float* stW2 = (const float*)d_in[5];
  const float* stb2 = (const float*)d_in[6];
  const float* aW1  = (const float*)d_in[7];
  const float* ab1  = (const float*)d_in[8];
  const float* aW2  = (const float*)d_in[9];
  const float* ab2  = (const float*)d_in[10];
  const float* oW1  = (const float*)d_in[11];
  const float* ob1  = (const float*)d_in[12];
  const float* oW2  = (const float*)d_in[13];
  const float* ob2  = (const float*)d_in[14];
  float* out = (float*)d_out;

  char* ws = (char*)d_ws;
  auto alloc = [&](size_t bytes) { char* p = ws; ws += (bytes + 255) & ~(size_t)255; return p; };
  float* state   = (float*)alloc((size_t)BATCH * EDIM * 4);
  float* initial = (float*)alloc((size_t)BATCH * EDIM * 4);
  int*   nn_all  = (int*)alloc(5 * BATCH * 4);

  k_embed_a0<<<BATCH / 4, 1024, 0, stream>>>(x, Wemb, bemb, aW1, ab1, aW2, ab2,
                                             state, initial, nn_all);
  for (int j = 0; j < 4; j++)
    k_block_mid<<<GRID_B, 1024, 0, stream>>>(state, stW1, stb1, stW2, stb2,
                                             aW1, ab1, aW2, ab2, nn_all, j);
  k_block_final<<<GRID_B, 1024, 0, stream>>>(state, stW1, stb1, stW2, stb2,
                                             initial, oW1, ob1, oW2, ob2,
                                             nn_all + 4 * BATCH, out);
}